// Round 1
// baseline (14015.231 us; speedup 1.0000x reference)
//
#include <hip/hip_runtime.h>
#include <math.h>

// ---------------- problem constants ----------------
#define B_    16
#define S_    512
#define IN_   258
#define ST_   512
#define RD_   128
#define M_    64
#define N_    512
#define H_    2
#define UPD_  404
#define UPH_  202
#define COLS_ 916          // recurrent output cols: state(512) + upd(404)
#define CPAD_ 920          // padded to 10*92
#define G_MM  10           // matmul blocks per batch
#define CPB_  92           // cols per matmul block
#define ROLES_ 11          // 10 matmul + 1 memory

// ---------------- workspace layout (float units) ----------------
#define XPART_F  (8192*CPAD_)        // 7,536,640
#define STATE_F  (B_*513*ST_)        // 4,202,496
#define READ_F   (B_*513*RD_)        // 1,050,624
#define UPDB_F   (2*B_*408)          // 13,056
#define NFLAGS_  (2*B_*513)          // arrive + go

struct SmemMM {
  float comb[640];          // [state(512) | read(128)]
  float part[5][CPB_];
};
struct SmemMB {
  float mem[64*513];        // mem[m][n] row-major, pad col -> conflict-free both ways
  float wt[2][512];
  float dyn[2][512];
  float wscr[2][512];
  float upd[408];
  float kn[2][64];
  float es[2][64];
  float ad[2][64];
  float rpart[2*8*64];      // [h][g][m]
  float red[16];
  float smalls[24];         // s[2][3],j[2][3],jd[2],gamma[2],beta[2],g[2],kinv[2]
};

__device__ __forceinline__ float sigm(float x){ return 1.f/(1.f+__expf(-x)); }
__device__ __forceinline__ float splus(float x){ return fmaxf(x,0.f)+log1pf(__expf(-fabsf(x))); }

__device__ __forceinline__ void redMax2(float&a,float&b,float* red,int tid){
  #pragma unroll
  for(int o=32;o;o>>=1){ a=fmaxf(a,__shfl_xor(a,o)); b=fmaxf(b,__shfl_xor(b,o)); }
  if((tid&63)==0){ red[(tid>>6)*2]=a; red[(tid>>6)*2+1]=b; }
  __syncthreads();
  a=red[0]; b=red[1];
  #pragma unroll
  for(int i=1;i<8;i++){ a=fmaxf(a,red[2*i]); b=fmaxf(b,red[2*i+1]); }
  __syncthreads();
}
__device__ __forceinline__ void redSum2(float&a,float&b,float* red,int tid){
  #pragma unroll
  for(int o=32;o;o>>=1){ a+=__shfl_xor(a,o); b+=__shfl_xor(b,o); }
  if((tid&63)==0){ red[(tid>>6)*2]=a; red[(tid>>6)*2+1]=b; }
  __syncthreads();
  a=red[0]; b=red[1];
  #pragma unroll
  for(int i=1;i<8;i++){ a+=red[2*i]; b+=red[2*i+1]; }
  __syncthreads();
}

__device__ __forceinline__ void spinGE(int* p, int target){
  int cnt=0;
  while(__hip_atomic_load(p, __ATOMIC_ACQUIRE, __HIP_MEMORY_SCOPE_AGENT) < target){
    __builtin_amdgcn_s_sleep(1);
    if(++cnt > (1<<24)) break;   // safety bail: terminate (wrong) rather than hang
  }
}

// P2: erase/add memory update fused with read(t+1) computation; writes readSeq + go flag
__device__ __forceinline__ void p2_step(SmemMB& S, int bb, int tnext,
    float* __restrict__ readSeq, int* __restrict__ go, int tid)
{
  const int m=tid&63, g=tid>>6;
  float e0=S.es[0][m], e1=S.es[1][m], a0=S.ad[0][m], a1=S.ad[1][m];
  float r0=0.f, r1=0.f;
  const int base=m*513;
  #pragma unroll 4
  for(int kk=0;kk<64;kk++){
    int n=g*64+kk;
    float w0=S.wt[0][n], w1=S.wt[1][n];
    float v=S.mem[base+n];
    float E=fmaf(e0,w0,e1*w1);
    float A=fmaf(a0,w0,a1*w1);
    v=fmaf(v,-E,v)+A;            // v*(1-E)+A
    S.mem[base+n]=v;
    r0=fmaf(w0,v,r0);
    r1=fmaf(w1,v,r1);
  }
  S.rpart[(0*8+g)*64+m]=r0;
  S.rpart[(1*8+g)*64+m]=r1;
  __syncthreads();
  if(tid<128){
    int h=tid>>6, mm=tid&63;
    float s=0.f;
    #pragma unroll
    for(int gg=0;gg<8;gg++) s+=S.rpart[(h*8+gg)*64+mm];
    readSeq[(size_t)(bb*513+tnext)*RD_+tid]=s;
  }
  __syncthreads();
  if(tid==0)
    __hip_atomic_store(&go[bb*513+tnext],1,__ATOMIC_RELEASE,__HIP_MEMORY_SCOPE_AGENT);
}

// ---------------- init: zero flags, state0 = ones ----------------
__global__ void init_kernel(float* __restrict__ stateSeq, int* __restrict__ flags, int nflags)
{
  int i = blockIdx.x*blockDim.x + threadIdx.x;
  if (i < nflags) flags[i] = 0;
  if (i < B_*ST_) { int b = i>>9, c = i&511; stateSeq[(size_t)(b*513)*ST_ + c] = 1.f; }
}

// ---------------- xpart = X @ W[0:258, state|upd] + bias ----------------
__global__ __launch_bounds__(256) void xpart_kernel(const float* __restrict__ X,
    const float* __restrict__ Ws, const float* __restrict__ Wu,
    const float* __restrict__ bs, const float* __restrict__ bu,
    float* __restrict__ xpart)
{
  __shared__ float Xs[32][65];
  __shared__ float Wsh[32][65];
  const int row0=blockIdx.x*64, c0=blockIdx.y*64;
  const int tid=threadIdx.x, tx=tid&15, ty=tid>>4;
  float acc[4][4]={};
  for(int k0=0;k0<IN_;k0+=32){
    for(int i=tid;i<32*64;i+=256){
      int kk=i&31, tt=i>>5, k=k0+kk;
      Xs[kk][tt]=(k<IN_)?X[(size_t)(row0+tt)*IN_+k]:0.f;
    }
    for(int i=tid;i<32*64;i+=256){
      int cc=i&63, kk=i>>6, k=k0+kk, c=c0+cc;
      float v=0.f;
      if(k<IN_){
        if(c<512) v=Ws[(size_t)k*512+c];
        else if(c<COLS_) v=Wu[(size_t)k*404+(c-512)];
      }
      Wsh[kk][cc]=v;
    }
    __syncthreads();
    #pragma unroll
    for(int kk=0;kk<32;kk++){
      float xv[4],wv[4];
      #pragma unroll
      for(int i=0;i<4;i++) xv[i]=Xs[kk][ty*4+i];
      #pragma unroll
      for(int j=0;j<4;j++) wv[j]=Wsh[kk][tx*4+j];
      #pragma unroll
      for(int i=0;i<4;i++)
        #pragma unroll
        for(int j=0;j<4;j++) acc[i][j]=fmaf(xv[i],wv[j],acc[i][j]);
    }
    __syncthreads();
  }
  #pragma unroll
  for(int i=0;i<4;i++){
    int r=row0+ty*4+i;
    #pragma unroll
    for(int j=0;j<4;j++){
      int c=c0+tx*4+j;
      if(c<COLS_){
        float bias=(c<512)?bs[c]:bu[c-512];
        xpart[(size_t)r*CPAD_+c]=acc[i][j]+bias;
      }
    }
  }
}

// ---------------- deferred output GEMM: out = sigmoid([x,state,read]@Wo + bo) ----------------
__global__ __launch_bounds__(256) void outgemm_kernel(const float* __restrict__ X,
    const float* __restrict__ stateSeq, const float* __restrict__ readSeq,
    const float* __restrict__ Wo, const float* __restrict__ bo, float* __restrict__ out)
{
  __shared__ float Cs[32][65];
  __shared__ float Wsh[32][65];
  const int row0=blockIdx.x*64, c0=blockIdx.y*64;
  const int tid=threadIdx.x, tx=tid&15, ty=tid>>4;
  float acc[4][4]={};
  for(int k0=0;k0<898;k0+=32){
    for(int i=tid;i<32*64;i+=256){
      int kk=i&31, tt=i>>5, k=k0+kk, row=row0+tt;
      float v=0.f;
      if(k<258) v=X[(size_t)row*IN_+k];
      else if(k<770){ int b=row>>9,t=row&511; v=stateSeq[(size_t)(b*513+t)*ST_+(k-258)]; }
      else if(k<898){ int b=row>>9,t=row&511; v=readSeq[(size_t)(b*513+t)*RD_+(k-770)]; }
      Cs[kk][tt]=v;
    }
    for(int i=tid;i<32*64;i+=256){
      int cc=i&63, kk=i>>6, k=k0+kk;
      Wsh[kk][cc]=(k<898)?Wo[(size_t)k*256+(c0+cc)]:0.f;
    }
    __syncthreads();
    #pragma unroll
    for(int kk=0;kk<32;kk++){
      float xv[4],wv[4];
      #pragma unroll
      for(int i=0;i<4;i++) xv[i]=Cs[kk][ty*4+i];
      #pragma unroll
      for(int j=0;j<4;j++) wv[j]=Wsh[kk][tx*4+j];
      #pragma unroll
      for(int i=0;i<4;i++)
        #pragma unroll
        for(int j=0;j<4;j++) acc[i][j]=fmaf(xv[i],wv[j],acc[i][j]);
    }
    __syncthreads();
  }
  #pragma unroll
  for(int i=0;i<4;i++){
    int r=row0+ty*4+i;
    #pragma unroll
    for(int j=0;j<4;j++){
      int c=c0+tx*4+j;
      out[(size_t)r*256+c]=sigm(acc[i][j]+bo[c]);
    }
  }
}

// ---------------- main persistent recurrent kernel ----------------
__global__ __launch_bounds__(512, 2) void main_kernel(
    const float* __restrict__ Ws, const float* __restrict__ Wu,
    const float* __restrict__ xpart, float* __restrict__ stateSeq,
    float* __restrict__ readSeq, float* __restrict__ updBuf,
    int* __restrict__ arrive, int* __restrict__ go)
{
  extern __shared__ char smem[];
  const int bb   = blockIdx.x / ROLES_;
  const int role = blockIdx.x % ROLES_;
  const int tid  = threadIdx.x;

  if (role < G_MM) {
    // ================= matmul block =================
    SmemMM& S = *(SmemMM*)smem;
    const int c  = tid % CPB_;
    const int rc = tid / CPB_;             // 0..4 active, 5 idle
    const int cg = role*CPB_ + c;
    const bool cvalid = (cg < COLS_);
    const float* Wp; int ldw, ci;
    if (cg < 512) { Wp = Ws; ldw = 512; ci = cg; }
    else          { Wp = Wu; ldw = 404; ci = cvalid ? (cg-512) : 0; }
    float wreg[128];
    if (rc < 5) {
      #pragma unroll 16
      for (int j = 0; j < 128; ++j)
        wreg[j] = Wp[(size_t)(258 + rc*128 + j)*ldw + ci];
    }
    for (int t = 0; t < S_; ++t) {
      // prefetch xpart early (independent of flags)
      float xp = 0.f;
      if (tid < CPB_ && cvalid) xp = xpart[(size_t)(bb*512 + t)*CPAD_ + cg];
      // phase A: state(t) ready once all peers finished step t-1
      if (t > 0) {
        if (tid == 0) spinGE(&arrive[bb*513 + (t-1)], G_MM);
        __syncthreads();
      }
      S.comb[tid] = stateSeq[(size_t)(bb*513 + t)*ST_ + tid];
      __syncthreads();
      float acc = 0.f;
      if (rc < 4) {                         // state rows 0..511
        const float4* cb = (const float4*)&S.comb[rc*128];
        #pragma unroll
        for (int j4 = 0; j4 < 32; ++j4) {
          float4 cv = cb[j4];
          acc = fmaf(cv.x, wreg[4*j4+0], acc);
          acc = fmaf(cv.y, wreg[4*j4+1], acc);
          acc = fmaf(cv.z, wreg[4*j4+2], acc);
          acc = fmaf(cv.w, wreg[4*j4+3], acc);
        }
      }
      // phase B: wait for read(t)
      if (tid == 0) spinGE(&go[bb*513 + t], 1);
      __syncthreads();
      if (tid < RD_) S.comb[512 + tid] = readSeq[(size_t)(bb*513 + t)*RD_ + tid];
      __syncthreads();
      if (rc == 4) {                        // read rows 512..639
        const float4* cb = (const float4*)&S.comb[512];
        #pragma unroll
        for (int j4 = 0; j4 < 32; ++j4) {
          float4 cv = cb[j4];
          acc = fmaf(cv.x, wreg[4*j4+0], acc);
          acc = fmaf(cv.y, wreg[4*j4+1], acc);
          acc = fmaf(cv.z, wreg[4*j4+2], acc);
          acc = fmaf(cv.w, wreg[4*j4+3], acc);
        }
      }
      if (rc < 5) S.part[rc][c] = acc;
      __syncthreads();
      if (tid < CPB_ && cvalid) {
        float pre = xp + S.part[0][c] + S.part[1][c] + S.part[2][c]
                       + S.part[3][c] + S.part[4][c];
        if (cg < 512)
          stateSeq[(size_t)(bb*513 + t + 1)*ST_ + cg] = sigm(pre);
        else
          updBuf[(size_t)((t&1)*B_ + bb)*408 + (cg - 512)] = pre;
      }
      __syncthreads();   // drain all threads' global stores before release
      if (tid == 0)
        __hip_atomic_fetch_add(&arrive[bb*513 + t], 1, __ATOMIC_RELEASE, __HIP_MEMORY_SCOPE_AGENT);
    }
  } else {
    // ================= memory block =================
    SmemMB& S = *(SmemMB*)smem;
    for (int i = tid; i < 64*513; i += 512) S.mem[i] = 0.01f;
    {
      float o0 = (tid == 0) ? 1.f : 0.f;
      S.wt[0][tid]=o0; S.wt[1][tid]=o0; S.dyn[0][tid]=o0; S.dyn[1][tid]=o0;
    }
    if (tid < 128) { S.es[tid>>6][tid&63]=0.f; S.ad[tid>>6][tid&63]=0.f; }
    __syncthreads();
    // prologue: P2 with zero erase/add == pure read_0 from initial wt/mem
    p2_step(S, bb, 0, readSeq, go, tid);

    for (int t = 0; t < S_-1; ++t) {
      if (tid == 0) spinGE(&arrive[bb*513 + t], G_MM);
      __syncthreads();
      for (int i = tid; i < UPD_; i += 512)
        S.upd[i] = updBuf[(size_t)((t&1)*B_ + bb)*408 + i];
      __syncthreads();
      if (tid < 2) {
        int h = tid; const float* u = &S.upd[h*UPH_];
        float sp0=splus(u[0]), sp1=splus(u[1]), sp2=splus(u[2]);
        float mx=fmaxf(sp0,fmaxf(sp1,sp2));
        float e0=__expf(sp0-mx), e1=__expf(sp1-mx), e2=__expf(sp2-mx);
        float inv=1.f/(e0+e1+e2);
        S.smalls[h*3+0]=e0*inv; S.smalls[h*3+1]=e1*inv; S.smalls[h*3+2]=e2*inv;
        float j0=u[4], j1=u[5], j2=u[6];
        float mj=fmaxf(j0,fmaxf(j1,j2));
        float f0=__expf(j0-mj), f1=__expf(j1-mj), f2=__expf(j2-mj);
        float invj=1.f/(f0+f1+f2);
        S.smalls[6+h*3+0]=f0*invj; S.smalls[6+h*3+1]=f1*invj; S.smalls[6+h*3+2]=f2*invj;
        S.smalls[12+h]=sigm(u[3]);           // jd
        S.smalls[14+h]=1.f+splus(u[7]);      // gamma
        S.smalls[16+h]=splus(u[200]);        // beta
        S.smalls[18+h]=sigm(u[201]);         // g
        float s2=0.f;
        for (int m=0;m<64;m++){ float kv=u[136+m]; s2=fmaf(kv,kv,s2); }
        S.smalls[20+h]=1.f/(sqrtf(s2)+1e-12f);  // kinv
      }
      if (tid < 128) {
        int h=tid>>6, m=tid&63; const float* u=&S.upd[h*UPH_];
        S.es[h][m]=sigm(u[8+m]);
        S.ad[h][m]=u[72+m];
      }
      __syncthreads();
      if (tid < 128) {
        int h=tid>>6, m=tid&63;
        S.kn[h][m]=S.upd[h*UPH_+136+m]*S.smalls[20+h];
      }
      __syncthreads();
      // ---- P1: column norms + cosine scores, softmax, mix, shift, sharpen ----
      {
        int n = tid;
        float nrm=0.f, d0=0.f, d1=0.f;
        #pragma unroll 8
        for (int m=0;m<64;m++){
          float v=S.mem[m*513+n];
          nrm=fmaf(v,v,nrm);
          d0=fmaf(S.kn[0][m],v,d0);
          d1=fmaf(S.kn[1][m],v,d1);
        }
        float inv=1.f/(sqrtf(nrm)+1e-12f);
        float sc0=S.smalls[16]*d0*inv, sc1=S.smalls[17]*d1*inv;
        float mx0=sc0, mx1=sc1; redMax2(mx0,mx1,S.red,tid);
        float ex0=__expf(sc0-mx0), ex1=__expf(sc1-mx1);
        float sm0=ex0, sm1=ex1; redSum2(sm0,sm1,S.red,tid);
        float wtk0=ex0/sm0, wtk1=ex1/sm1;
        float jd0=S.smalls[12], jd1=S.smalls[13];
        float g0=S.smalls[18],  g1=S.smalls[19];
        float w0o=S.wt[0][n], w1o=S.wt[1][n];
        float dn0=fmaf(jd0, w0o - S.dyn[0][n], S.dyn[0][n]);
        float dn1=fmaf(jd1, w1o - S.dyn[1][n], S.dyn[1][n]);
        S.dyn[0][n]=dn0; S.dyn[1][n]=dn1;
        float fx=(n==0)?1.f:0.f;
        float wm0=S.smalls[6+0]*w0o + S.smalls[6+1]*dn0 + S.smalls[6+2]*fx;
        float wm1=S.smalls[9+0]*w1o + S.smalls[9+1]*dn1 + S.smalls[9+2]*fx;
        float wc0=fmaf(g0, wtk0-wm0, wm0);
        float wc1=fmaf(g1, wtk1-wm1, wm1);
        S.wscr[0][n]=wc0; S.wscr[1][n]=wc1;
        __syncthreads();
        int np=(n+1)&511, nm=(n-1)&511;
        float wsh0=S.smalls[0]*S.wscr[0][np]+S.smalls[1]*S.wscr[0][n]+S.smalls[2]*S.wscr[0][nm];
        float wsh1=S.smalls[3]*S.wscr[1][np]+S.smalls[4]*S.wscr[1][n]+S.smalls[5]*S.wscr[1][nm];
        float gam0=S.smalls[14], gam1=S.smalls[15];
        float wp0=(wsh0>0.f)?__expf(gam0*__logf(wsh0)):0.f;
        float wp1=(wsh1>0.f)?__expf(gam1*__logf(wsh1)):0.f;
        float ds0=wp0, ds1=wp1; redSum2(ds0,ds1,S.red,tid);
        S.wt[0][n]=wp0/(ds0+1e-12f);
        S.wt[1][n]=wp1/(ds1+1e-12f);
      }
      __syncthreads();
      // ---- P2: mem update + read(t+1) + flag ----
      p2_step(S, bb, t+1, readSeq, go, tid);
    }
  }
}

// ---------------- launch ----------------
extern "C" void kernel_launch(void* const* d_in, const int* in_sizes, int n_in,
                              void* d_out, int out_size, void* d_ws, size_t ws_size,
                              hipStream_t stream) {
  (void)in_sizes; (void)n_in; (void)out_size;
  const float* X  = (const float*)d_in[0];
  const float* Ws = (const float*)d_in[1];
  const float* bs = (const float*)d_in[2];
  const float* Wo = (const float*)d_in[3];
  const float* bo = (const float*)d_in[4];
  const float* Wu = (const float*)d_in[5];
  const float* bu = (const float*)d_in[6];
  float* out = (float*)d_out;

  const size_t needed = (size_t)(XPART_F + STATE_F + READ_F + UPDB_F)*4 + (size_t)NFLAGS_*4;
  if (ws_size < needed) return;   // fail visibly rather than corrupt memory

  float* xpart    = (float*)d_ws;
  float* stateSeq = xpart + XPART_F;
  float* readSeq  = stateSeq + STATE_F;
  float* updBuf   = readSeq + READ_F;
  int*   flags    = (int*)(updBuf + UPDB_F);
  int*   arrive   = flags;
  int*   go       = flags + B_*513;

  hipLaunchKernelGGL(init_kernel, dim3(65), dim3(256), 0, stream, stateSeq, flags, NFLAGS_);
  hipLaunchKernelGGL(xpart_kernel, dim3(128, 15), dim3(256), 0, stream, X, Ws, Wu, bs, bu, xpart);

  (void)hipFuncSetAttribute((const void*)main_kernel,
        hipFuncAttributeMaxDynamicSharedMemorySize, (int)sizeof(SmemMB));
  void* kargs[] = { (void*)&Ws, (void*)&Wu, (void*)&xpart, (void*)&stateSeq,
                    (void*)&readSeq, (void*)&updBuf, (void*)&arrive, (void*)&go };
  hipLaunchCooperativeKernel((const void*)main_kernel, dim3(B_*ROLES_), dim3(512),
                             kargs, (unsigned)sizeof(SmemMB), stream);

  hipLaunchKernelGGL(outgemm_kernel, dim3(128, 4), dim3(256), 0, stream,
                     X, stateSeq, readSeq, Wo, bo, out);
}

// Round 2
// 11392.509 us; speedup vs baseline: 1.2302x; 1.2302x over previous
//
#include <hip/hip_runtime.h>
#include <math.h>

// ---------------- problem constants ----------------
#define B_    16
#define S_    512
#define IN_   258
#define ST_   512
#define RD_   128
#define M_    64
#define N_    512
#define H_    2
#define UPD_  404
#define UPH_  202
#define COLS_ 916          // recurrent output cols: state(512) + upd(404)
#define CPAD_ 920          // padded to 10*92
#define G_MM  10           // matmul blocks per batch
#define CPB_  92           // cols per matmul block
#define ROLES_ 11          // 10 matmul + 1 memory

// ---------------- workspace layout (float units) ----------------
#define XPART_F  (8192*CPAD_)        // 7,536,640
#define STATE_F  (B_*513*ST_)        // 4,202,496
#define READ_F   (B_*513*RD_)        // 1,050,624
#define UPDB_F   (2*B_*408)          // 13,056
#define ARRF_N   (B_*S_*16)          // per-role arrive flag lines (16 ints = 64B per (b,t))
#define GO_N     (B_*513)
#define NFLAGS_  (ARRF_N + GO_N)

// Relaxed agent-scope atomics: compile to global_load/store with sc0 sc1
// (bypass non-coherent L1/L2, operate at LLC). NO buffer_inv / buffer_wbl2.
#define AT_LD(p)    __hip_atomic_load((p), __ATOMIC_RELAXED, __HIP_MEMORY_SCOPE_AGENT)
#define AT_ST(p,v)  __hip_atomic_store((p), (v), __ATOMIC_RELAXED, __HIP_MEMORY_SCOPE_AGENT)

struct SmemMM {
  float comb[640];          // [state(512) | read(128)]
  float part[5][CPB_];
};
struct SmemMB {
  float mem[64*513];        // mem[m][n] row-major, pad col -> conflict-free both ways
  float wt[2][512];
  float dyn[2][512];
  float wscr[2][512];
  float upd[408];
  float kn[2][64];
  float es[2][64];
  float ad[2][64];
  float rpart[2*8*64];      // [h][g][m]
  float red[16];
  float smalls[24];         // s[2][3],j[2][3],jd[2],gamma[2],beta[2],g[2],kinv[2]
};

__device__ __forceinline__ float sigm(float x){ return 1.f/(1.f+__expf(-x)); }
__device__ __forceinline__ float splus(float x){ return fmaxf(x,0.f)+log1pf(__expf(-fabsf(x))); }

__device__ __forceinline__ void redMax2(float&a,float&b,float* red,int tid){
  #pragma unroll
  for(int o=32;o;o>>=1){ a=fmaxf(a,__shfl_xor(a,o)); b=fmaxf(b,__shfl_xor(b,o)); }
  if((tid&63)==0){ red[(tid>>6)*2]=a; red[(tid>>6)*2+1]=b; }
  __syncthreads();
  a=red[0]; b=red[1];
  #pragma unroll
  for(int i=1;i<8;i++){ a=fmaxf(a,red[2*i]); b=fmaxf(b,red[2*i+1]); }
  __syncthreads();
}
__device__ __forceinline__ void redSum2(float&a,float&b,float* red,int tid){
  #pragma unroll
  for(int o=32;o;o>>=1){ a+=__shfl_xor(a,o); b+=__shfl_xor(b,o); }
  if((tid&63)==0){ red[(tid>>6)*2]=a; red[(tid>>6)*2+1]=b; }
  __syncthreads();
  a=red[0]; b=red[1];
  #pragma unroll
  for(int i=1;i<8;i++){ a+=red[2*i]; b+=red[2*i+1]; }
  __syncthreads();
}

// poll a single go flag (relaxed — no cache maintenance per iteration)
__device__ __forceinline__ void spinGE1(const int* p){
  int cnt=0;
  while(AT_LD(p)==0){
    __builtin_amdgcn_s_sleep(1);
    if(++cnt > (1<<22)) break;   // safety bail: wrong output rather than hang
  }
}
// poll a 16-int flag line until roles 0..9 all set (10 pipelined LLC loads/iter)
__device__ __forceinline__ void waitLine10(const int* f){
  int cnt=0;
  for(;;){
    int ok=1;
    #pragma unroll
    for(int r=0;r<10;r++) ok &= (AT_LD(f+r) != 0);
    if(ok) break;
    __builtin_amdgcn_s_sleep(1);
    if(++cnt > (1<<22)) break;
  }
}

// P2: erase/add memory update fused with read(t+1) computation; writes readSeq + go flag
__device__ __forceinline__ void p2_step(SmemMB& S, int bb, int tnext,
    float* __restrict__ readSeq, int* __restrict__ go, int tid)
{
  const int m=tid&63, g=tid>>6;
  float e0=S.es[0][m], e1=S.es[1][m], a0=S.ad[0][m], a1=S.ad[1][m];
  float r0=0.f, r1=0.f;
  const int base=m*513;
  #pragma unroll 4
  for(int kk=0;kk<64;kk++){
    int n=g*64+kk;
    float w0=S.wt[0][n], w1=S.wt[1][n];
    float v=S.mem[base+n];
    float E=fmaf(e0,w0,e1*w1);
    float A=fmaf(a0,w0,a1*w1);
    v=fmaf(v,-E,v)+A;            // v*(1-E)+A
    S.mem[base+n]=v;
    r0=fmaf(w0,v,r0);
    r1=fmaf(w1,v,r1);
  }
  S.rpart[(0*8+g)*64+m]=r0;
  S.rpart[(1*8+g)*64+m]=r1;
  __syncthreads();
  if(tid<128){
    int h=tid>>6, mm=tid&63;
    float s=0.f;
    #pragma unroll
    for(int gg=0;gg<8;gg++) s+=S.rpart[(h*8+gg)*64+mm];
    AT_ST(&readSeq[(size_t)(bb*513+tnext)*RD_+tid], s);
  }
  __syncthreads();               // drains vmcnt(0) for all waves' stores
  if(tid==0)
    AT_ST(&go[bb*513+tnext], 1);
}

// ---------------- init: zero flags, state0 = ones ----------------
__global__ void init_kernel(float* __restrict__ stateSeq, int* __restrict__ flags, int nflags)
{
  int i = blockIdx.x*blockDim.x + threadIdx.x;
  if (i < nflags) flags[i] = 0;
  if (i < B_*ST_) { int b = i>>9, c = i&511; stateSeq[(size_t)(b*513)*ST_ + c] = 1.f; }
}

// ---------------- xpart = X @ W[0:258, state|upd] + bias ----------------
__global__ __launch_bounds__(256) void xpart_kernel(const float* __restrict__ X,
    const float* __restrict__ Ws, const float* __restrict__ Wu,
    const float* __restrict__ bs, const float* __restrict__ bu,
    float* __restrict__ xpart)
{
  __shared__ float Xs[32][65];
  __shared__ float Wsh[32][65];
  const int row0=blockIdx.x*64, c0=blockIdx.y*64;
  const int tid=threadIdx.x, tx=tid&15, ty=tid>>4;
  float acc[4][4]={};
  for(int k0=0;k0<IN_;k0+=32){
    for(int i=tid;i<32*64;i+=256){
      int kk=i&31, tt=i>>5, k=k0+kk;
      Xs[kk][tt]=(k<IN_)?X[(size_t)(row0+tt)*IN_+k]:0.f;
    }
    for(int i=tid;i<32*64;i+=256){
      int cc=i&63, kk=i>>6, k=k0+kk, c=c0+cc;
      float v=0.f;
      if(k<IN_){
        if(c<512) v=Ws[(size_t)k*512+c];
        else if(c<COLS_) v=Wu[(size_t)k*404+(c-512)];
      }
      Wsh[kk][cc]=v;
    }
    __syncthreads();
    #pragma unroll
    for(int kk=0;kk<32;kk++){
      float xv[4],wv[4];
      #pragma unroll
      for(int i=0;i<4;i++) xv[i]=Xs[kk][ty*4+i];
      #pragma unroll
      for(int j=0;j<4;j++) wv[j]=Wsh[kk][tx*4+j];
      #pragma unroll
      for(int i=0;i<4;i++)
        #pragma unroll
        for(int j=0;j<4;j++) acc[i][j]=fmaf(xv[i],wv[j],acc[i][j]);
    }
    __syncthreads();
  }
  #pragma unroll
  for(int i=0;i<4;i++){
    int r=row0+ty*4+i;
    #pragma unroll
    for(int j=0;j<4;j++){
      int c=c0+tx*4+j;
      if(c<COLS_){
        float bias=(c<512)?bs[c]:bu[c-512];
        xpart[(size_t)r*CPAD_+c]=acc[i][j]+bias;
      }
    }
  }
}

// ---------------- deferred output GEMM: out = sigmoid([x,state,read]@Wo + bo) ----------------
__global__ __launch_bounds__(256) void outgemm_kernel(const float* __restrict__ X,
    const float* __restrict__ stateSeq, const float* __restrict__ readSeq,
    const float* __restrict__ Wo, const float* __restrict__ bo, float* __restrict__ out)
{
  __shared__ float Cs[32][65];
  __shared__ float Wsh[32][65];
  const int row0=blockIdx.x*64, c0=blockIdx.y*64;
  const int tid=threadIdx.x, tx=tid&15, ty=tid>>4;
  float acc[4][4]={};
  for(int k0=0;k0<898;k0+=32){
    for(int i=tid;i<32*64;i+=256){
      int kk=i&31, tt=i>>5, k=k0+kk, row=row0+tt;
      float v=0.f;
      if(k<258) v=X[(size_t)row*IN_+k];
      else if(k<770){ int b=row>>9,t=row&511; v=stateSeq[(size_t)(b*513+t)*ST_+(k-258)]; }
      else if(k<898){ int b=row>>9,t=row&511; v=readSeq[(size_t)(b*513+t)*RD_+(k-770)]; }
      Cs[kk][tt]=v;
    }
    for(int i=tid;i<32*64;i+=256){
      int cc=i&63, kk=i>>6, k=k0+kk;
      Wsh[kk][cc]=(k<898)?Wo[(size_t)k*256+(c0+cc)]:0.f;
    }
    __syncthreads();
    #pragma unroll
    for(int kk=0;kk<32;kk++){
      float xv[4],wv[4];
      #pragma unroll
      for(int i=0;i<4;i++) xv[i]=Cs[kk][ty*4+i];
      #pragma unroll
      for(int j=0;j<4;j++) wv[j]=Wsh[kk][tx*4+j];
      #pragma unroll
      for(int i=0;i<4;i++)
        #pragma unroll
        for(int j=0;j<4;j++) acc[i][j]=fmaf(xv[i],wv[j],acc[i][j]);
    }
    __syncthreads();
  }
  #pragma unroll
  for(int i=0;i<4;i++){
    int r=row0+ty*4+i;
    #pragma unroll
    for(int j=0;j<4;j++){
      int c=c0+tx*4+j;
      out[(size_t)r*256+c]=sigm(acc[i][j]+bo[c]);
    }
  }
}

// ---------------- main persistent recurrent kernel ----------------
__global__ __launch_bounds__(512, 2) void main_kernel(
    const float* __restrict__ Ws, const float* __restrict__ Wu,
    const float* __restrict__ xpart, float* __restrict__ stateSeq,
    float* __restrict__ readSeq, float* __restrict__ updBuf,
    int* __restrict__ arriveF, int* __restrict__ go)
{
  extern __shared__ char smem[];
  const int bb   = blockIdx.x / ROLES_;
  const int role = blockIdx.x % ROLES_;
  const int tid  = threadIdx.x;

  if (role < G_MM) {
    // ================= matmul block =================
    SmemMM& S = *(SmemMM*)smem;
    const int c  = tid % CPB_;
    const int rc = tid / CPB_;             // 0..4 active, 5 idle
    const int cg = role*CPB_ + c;
    const bool cvalid = (cg < COLS_);
    const float* Wp; int ldw, ci;
    if (cg < 512) { Wp = Ws; ldw = 512; ci = cg; }
    else          { Wp = Wu; ldw = 404; ci = cvalid ? (cg-512) : 0; }
    float wreg[128];
    if (rc < 5) {
      #pragma unroll 16
      for (int j = 0; j < 128; ++j)
        wreg[j] = Wp[(size_t)(258 + rc*128 + j)*ldw + ci];
    }
    for (int t = 0; t < S_; ++t) {
      // prefetch xpart early (normal cached load, read-only data)
      float xp = 0.f;
      if (tid < CPB_ && cvalid) xp = xpart[(size_t)(bb*512 + t)*CPAD_ + cg];
      // phase A: state(t) ready once all peers finished step t-1
      if (t > 0) {
        if (tid == 0) waitLine10(&arriveF[(size_t)(bb*512 + (t-1))*16]);
        __syncthreads();
      }
      S.comb[tid] = AT_LD(&stateSeq[(size_t)(bb*513 + t)*ST_ + tid]);
      __syncthreads();
      float acc = 0.f;
      if (rc < 4) {                         // state rows 0..511
        const float4* cb = (const float4*)&S.comb[rc*128];
        #pragma unroll
        for (int j4 = 0; j4 < 32; ++j4) {
          float4 cv = cb[j4];
          acc = fmaf(cv.x, wreg[4*j4+0], acc);
          acc = fmaf(cv.y, wreg[4*j4+1], acc);
          acc = fmaf(cv.z, wreg[4*j4+2], acc);
          acc = fmaf(cv.w, wreg[4*j4+3], acc);
        }
      }
      // phase B: wait for read(t)
      if (tid == 0) spinGE1(&go[bb*513 + t]);
      __syncthreads();
      if (tid < RD_) S.comb[512 + tid] = AT_LD(&readSeq[(size_t)(bb*513 + t)*RD_ + tid]);
      __syncthreads();
      if (rc == 4) {                        // read rows 512..639
        const float4* cb = (const float4*)&S.comb[512];
        #pragma unroll
        for (int j4 = 0; j4 < 32; ++j4) {
          float4 cv = cb[j4];
          acc = fmaf(cv.x, wreg[4*j4+0], acc);
          acc = fmaf(cv.y, wreg[4*j4+1], acc);
          acc = fmaf(cv.z, wreg[4*j4+2], acc);
          acc = fmaf(cv.w, wreg[4*j4+3], acc);
        }
      }
      if (rc < 5) S.part[rc][c] = acc;
      __syncthreads();
      if (tid < CPB_ && cvalid) {
        float pre = xp + S.part[0][c] + S.part[1][c] + S.part[2][c]
                       + S.part[3][c] + S.part[4][c];
        if (cg < 512)
          AT_ST(&stateSeq[(size_t)(bb*513 + t + 1)*ST_ + cg], sigm(pre));
        else
          AT_ST(&updBuf[(size_t)((t&1)*B_ + bb)*408 + (cg - 512)], pre);
      }
      __syncthreads();   // drains vmcnt(0) in every wave before the flag store
      if (tid == 0)
        AT_ST(&arriveF[(size_t)(bb*512 + t)*16 + role], 1);
    }
  } else {
    // ================= memory block =================
    SmemMB& S = *(SmemMB*)smem;
    for (int i = tid; i < 64*513; i += 512) S.mem[i] = 0.01f;
    {
      float o0 = (tid == 0) ? 1.f : 0.f;
      S.wt[0][tid]=o0; S.wt[1][tid]=o0; S.dyn[0][tid]=o0; S.dyn[1][tid]=o0;
    }
    if (tid < 128) { S.es[tid>>6][tid&63]=0.f; S.ad[tid>>6][tid&63]=0.f; }
    __syncthreads();
    // prologue: P2 with zero erase/add == pure read_0 from initial wt/mem
    p2_step(S, bb, 0, readSeq, go, tid);

    for (int t = 0; t < S_-1; ++t) {
      if (tid == 0) waitLine10(&arriveF[(size_t)(bb*512 + t)*16]);
      __syncthreads();
      for (int i = tid; i < UPD_; i += 512)
        S.upd[i] = AT_LD(&updBuf[(size_t)((t&1)*B_ + bb)*408 + i]);
      __syncthreads();
      if (tid < 2) {
        int h = tid; const float* u = &S.upd[h*UPH_];
        float sp0=splus(u[0]), sp1=splus(u[1]), sp2=splus(u[2]);
        float mx=fmaxf(sp0,fmaxf(sp1,sp2));
        float e0=__expf(sp0-mx), e1=__expf(sp1-mx), e2=__expf(sp2-mx);
        float inv=1.f/(e0+e1+e2);
        S.smalls[h*3+0]=e0*inv; S.smalls[h*3+1]=e1*inv; S.smalls[h*3+2]=e2*inv;
        float j0=u[4], j1=u[5], j2=u[6];
        float mj=fmaxf(j0,fmaxf(j1,j2));
        float f0=__expf(j0-mj), f1=__expf(j1-mj), f2=__expf(j2-mj);
        float invj=1.f/(f0+f1+f2);
        S.smalls[6+h*3+0]=f0*invj; S.smalls[6+h*3+1]=f1*invj; S.smalls[6+h*3+2]=f2*invj;
        S.smalls[12+h]=sigm(u[3]);           // jd
        S.smalls[14+h]=1.f+splus(u[7]);      // gamma
        S.smalls[16+h]=splus(u[200]);        // beta
        S.smalls[18+h]=sigm(u[201]);         // g
        float s2=0.f;
        for (int m=0;m<64;m++){ float kv=u[136+m]; s2=fmaf(kv,kv,s2); }
        S.smalls[20+h]=1.f/(sqrtf(s2)+1e-12f);  // kinv
      }
      if (tid < 128) {
        int h=tid>>6, m=tid&63; const float* u=&S.upd[h*UPH_];
        S.es[h][m]=sigm(u[8+m]);
        S.ad[h][m]=u[72+m];
      }
      __syncthreads();
      if (tid < 128) {
        int h=tid>>6, m=tid&63;
        S.kn[h][m]=S.upd[h*UPH_+136+m]*S.smalls[20+h];
      }
      __syncthreads();
      // ---- P1: column norms + cosine scores, softmax, mix, shift, sharpen ----
      {
        int n = tid;
        float nrm=0.f, d0=0.f, d1=0.f;
        #pragma unroll 8
        for (int m=0;m<64;m++){
          float v=S.mem[m*513+n];
          nrm=fmaf(v,v,nrm);
          d0=fmaf(S.kn[0][m],v,d0);
          d1=fmaf(S.kn[1][m],v,d1);
        }
        float inv=1.f/(sqrtf(nrm)+1e-12f);
        float sc0=S.smalls[16]*d0*inv, sc1=S.smalls[17]*d1*inv;
        float mx0=sc0, mx1=sc1; redMax2(mx0,mx1,S.red,tid);
        float ex0=__expf(sc0-mx0), ex1=__expf(sc1-mx1);
        float sm0=ex0, sm1=ex1; redSum2(sm0,sm1,S.red,tid);
        float wtk0=ex0/sm0, wtk1=ex1/sm1;
        float jd0=S.smalls[12], jd1=S.smalls[13];
        float g0=S.smalls[18],  g1=S.smalls[19];
        float w0o=S.wt[0][n], w1o=S.wt[1][n];
        float dn0=fmaf(jd0, w0o - S.dyn[0][n], S.dyn[0][n]);
        float dn1=fmaf(jd1, w1o - S.dyn[1][n], S.dyn[1][n]);
        S.dyn[0][n]=dn0; S.dyn[1][n]=dn1;
        float fx=(n==0)?1.f:0.f;
        float wm0=S.smalls[6+0]*w0o + S.smalls[6+1]*dn0 + S.smalls[6+2]*fx;
        float wm1=S.smalls[9+0]*w1o + S.smalls[9+1]*dn1 + S.smalls[9+2]*fx;
        float wc0=fmaf(g0, wtk0-wm0, wm0);
        float wc1=fmaf(g1, wtk1-wm1, wm1);
        S.wscr[0][n]=wc0; S.wscr[1][n]=wc1;
        __syncthreads();
        int np=(n+1)&511, nm=(n-1)&511;
        float wsh0=S.smalls[0]*S.wscr[0][np]+S.smalls[1]*S.wscr[0][n]+S.smalls[2]*S.wscr[0][nm];
        float wsh1=S.smalls[3]*S.wscr[1][np]+S.smalls[4]*S.wscr[1][n]+S.smalls[5]*S.wscr[1][nm];
        float gam0=S.smalls[14], gam1=S.smalls[15];
        float wp0=(wsh0>0.f)?__expf(gam0*__logf(wsh0)):0.f;
        float wp1=(wsh1>0.f)?__expf(gam1*__logf(wsh1)):0.f;
        float ds0=wp0, ds1=wp1; redSum2(ds0,ds1,S.red,tid);
        S.wt[0][n]=wp0/(ds0+1e-12f);
        S.wt[1][n]=wp1/(ds1+1e-12f);
      }
      __syncthreads();
      // ---- P2: mem update + read(t+1) + flag ----
      p2_step(S, bb, t+1, readSeq, go, tid);
    }
  }
}

// ---------------- launch ----------------
extern "C" void kernel_launch(void* const* d_in, const int* in_sizes, int n_in,
                              void* d_out, int out_size, void* d_ws, size_t ws_size,
                              hipStream_t stream) {
  (void)in_sizes; (void)n_in; (void)out_size;
  const float* X  = (const float*)d_in[0];
  const float* Ws = (const float*)d_in[1];
  const float* bs = (const float*)d_in[2];
  const float* Wo = (const float*)d_in[3];
  const float* bo = (const float*)d_in[4];
  const float* Wu = (const float*)d_in[5];
  const float* bu = (const float*)d_in[6];
  float* out = (float*)d_out;

  const size_t needed = (size_t)(XPART_F + STATE_F + READ_F + UPDB_F)*4 + (size_t)NFLAGS_*4;
  if (ws_size < needed) return;   // fail visibly rather than corrupt memory

  float* xpart    = (float*)d_ws;
  float* stateSeq = xpart + XPART_F;
  float* readSeq  = stateSeq + STATE_F;
  float* updBuf   = readSeq + READ_F;
  int*   flags    = (int*)(updBuf + UPDB_F);
  int*   arriveF  = flags;                 // B_*S_*16 ints, 64B line per (b,t)
  int*   go       = flags + ARRF_N;        // B_*513 ints

  hipLaunchKernelGGL(init_kernel, dim3((NFLAGS_ + 255)/256), dim3(256), 0, stream,
                     stateSeq, flags, NFLAGS_);
  hipLaunchKernelGGL(xpart_kernel, dim3(128, 15), dim3(256), 0, stream, X, Ws, Wu, bs, bu, xpart);

  (void)hipFuncSetAttribute((const void*)main_kernel,
        hipFuncAttributeMaxDynamicSharedMemorySize, (int)sizeof(SmemMB));
  void* kargs[] = { (void*)&Ws, (void*)&Wu, (void*)&xpart, (void*)&stateSeq,
                    (void*)&readSeq, (void*)&updBuf, (void*)&arriveF, (void*)&go };
  hipLaunchCooperativeKernel((const void*)main_kernel, dim3(B_*ROLES_), dim3(512),
                             kargs, (unsigned)sizeof(SmemMB), stream);

  hipLaunchKernelGGL(outgemm_kernel, dim3(128, 4), dim3(256), 0, stream,
                     X, stateSeq, readSeq, Wo, bo, out);
}

// Round 3
// 6842.154 us; speedup vs baseline: 2.0484x; 1.6650x over previous
//
#include <hip/hip_runtime.h>
#include <math.h>

// ---------------- problem constants ----------------
#define B_    16
#define S_    512
#define IN_   258
#define ST_   512
#define RD_   128
#define M_    64
#define N_    512
#define H_    2
#define UPD_  404
#define UPH_  202
#define COLS_ 916          // recurrent output cols: state(512) + upd(404)
#define CPAD_ 920          // padded to 10*92
#define G_MM  10           // matmul blocks per batch
#define CPB_  92           // cols per matmul block
#define ROLES_ 11          // 10 matmul + 1 memory

// ---------------- workspace layout (float units) ----------------
#define XPART_F  (8192*CPAD_)        // 7,536,640
#define STATE_F  (B_*513*ST_)        // 4,202,496
#define READ_F   (B_*513*RD_)        // 1,050,624
#define UPDB_F   (2*B_*408)          // 13,056
#define NFLAGS_  (2*B_*S_ + B_*513)  // arriveS + arriveU + go

// Relaxed agent-scope atomics: plain global_load/store sc0 sc1 (LLC-direct,
// bypass non-coherent L1/L2). No buffer_inv / buffer_wbl2 ever.
#define AT_LD(p)    __hip_atomic_load((p), __ATOMIC_RELAXED, __HIP_MEMORY_SCOPE_AGENT)
#define AT_ST(p,v)  __hip_atomic_store((p), (v), __ATOMIC_RELAXED, __HIP_MEMORY_SCOPE_AGENT)
#define AT_ADD(p)   __hip_atomic_fetch_add((p), 1, __ATOMIC_RELAXED, __HIP_MEMORY_SCOPE_AGENT)

struct SmemMM {
  float comb[640];          // [state(512) | read(128)]
  float part[5][CPB_];
};
struct SmemMB {
  float mem[64*513];        // mem[m][n] row-major, pad col -> conflict-free both ways
  float wt[2][512];
  float dyn[2][512];
  float wscr[2][512];
  float upd[408];
  float kn[2][64];
  float es[2][64];
  float ad[2][64];
  float rpart[2*8*64];      // [h][g][m]
  float red[16];
  float smalls[24];         // s[2][3],j[2][3],jd[2],gamma[2],beta[2],g[2],kinv[2]
};

__device__ __forceinline__ float sigm(float x){ return 1.f/(1.f+__expf(-x)); }
__device__ __forceinline__ float splus(float x){ return fmaxf(x,0.f)+log1pf(__expf(-fabsf(x))); }

__device__ __forceinline__ void redMax2(float&a,float&b,float* red,int tid){
  #pragma unroll
  for(int o=32;o;o>>=1){ a=fmaxf(a,__shfl_xor(a,o)); b=fmaxf(b,__shfl_xor(b,o)); }
  if((tid&63)==0){ red[(tid>>6)*2]=a; red[(tid>>6)*2+1]=b; }
  __syncthreads();
  a=red[0]; b=red[1];
  #pragma unroll
  for(int i=1;i<8;i++){ a=fmaxf(a,red[2*i]); b=fmaxf(b,red[2*i+1]); }
  __syncthreads();
}
__device__ __forceinline__ void redSum2(float&a,float&b,float* red,int tid){
  #pragma unroll
  for(int o=32;o;o>>=1){ a+=__shfl_xor(a,o); b+=__shfl_xor(b,o); }
  if((tid&63)==0){ red[(tid>>6)*2]=a; red[(tid>>6)*2+1]=b; }
  __syncthreads();
  a=red[0]; b=red[1];
  #pragma unroll
  for(int i=1;i<8;i++){ a+=red[2*i]; b+=red[2*i+1]; }
  __syncthreads();
}

// poll one counter word until >= target (single 64B line per iteration)
__device__ __forceinline__ void spinCnt(const int* p, int target){
  int c=0;
  while(AT_LD(p) < target){
    __builtin_amdgcn_s_sleep(1);
    if(++c > (1<<22)) break;   // safety bail: wrong output rather than hang
  }
}

// P2: erase/add memory update fused with read(t+1) computation; writes readSeq + go flag
__device__ __forceinline__ void p2_step(SmemMB& S, int bb, int tnext,
    float* __restrict__ readSeq, int* __restrict__ go, int tid)
{
  const int m=tid&63, g=tid>>6;
  float e0=S.es[0][m], e1=S.es[1][m], a0=S.ad[0][m], a1=S.ad[1][m];
  float r0=0.f, r1=0.f;
  const int base=m*513;
  #pragma unroll 4
  for(int kk=0;kk<64;kk++){
    int n=g*64+kk;
    float w0=S.wt[0][n], w1=S.wt[1][n];
    float v=S.mem[base+n];
    float E=fmaf(e0,w0,e1*w1);
    float A=fmaf(a0,w0,a1*w1);
    v=fmaf(v,-E,v)+A;            // v*(1-E)+A
    S.mem[base+n]=v;
    r0=fmaf(w0,v,r0);
    r1=fmaf(w1,v,r1);
  }
  S.rpart[(0*8+g)*64+m]=r0;
  S.rpart[(1*8+g)*64+m]=r1;
  __syncthreads();
  if(tid<128){
    int h=tid>>6, mm=tid&63;
    float s=0.f;
    #pragma unroll
    for(int gg=0;gg<8;gg++) s+=S.rpart[(h*8+gg)*64+mm];
    AT_ST(&readSeq[(size_t)(bb*513+tnext)*RD_+tid], s);
  }
  __syncthreads();               // drains vmcnt(0) for all waves' stores
  if(tid==0)
    AT_ST(&go[bb*513+tnext], 1);
}

// ---------------- init: zero flags, state0 = ones ----------------
__global__ void init_kernel(float* __restrict__ stateSeq, int* __restrict__ flags, int nflags)
{
  int i = blockIdx.x*blockDim.x + threadIdx.x;
  if (i < nflags) flags[i] = 0;
  if (i < B_*ST_) { int b = i>>9, c = i&511; stateSeq[(size_t)(b*513)*ST_ + c] = 1.f; }
}

// ---------------- xpart = X @ W[0:258, state|upd] + bias ----------------
__global__ __launch_bounds__(256) void xpart_kernel(const float* __restrict__ X,
    const float* __restrict__ Ws, const float* __restrict__ Wu,
    const float* __restrict__ bs, const float* __restrict__ bu,
    float* __restrict__ xpart)
{
  __shared__ float Xs[32][65];
  __shared__ float Wsh[32][65];
  const int row0=blockIdx.x*64, c0=blockIdx.y*64;
  const int tid=threadIdx.x, tx=tid&15, ty=tid>>4;
  float acc[4][4]={};
  for(int k0=0;k0<IN_;k0+=32){
    for(int i=tid;i<32*64;i+=256){
      int kk=i&31, tt=i>>5, k=k0+kk;
      Xs[kk][tt]=(k<IN_)?X[(size_t)(row0+tt)*IN_+k]:0.f;
    }
    for(int i=tid;i<32*64;i+=256){
      int cc=i&63, kk=i>>6, k=k0+kk, c=c0+cc;
      float v=0.f;
      if(k<IN_){
        if(c<512) v=Ws[(size_t)k*512+c];
        else if(c<COLS_) v=Wu[(size_t)k*404+(c-512)];
      }
      Wsh[kk][cc]=v;
    }
    __syncthreads();
    #pragma unroll
    for(int kk=0;kk<32;kk++){
      float xv[4],wv[4];
      #pragma unroll
      for(int i=0;i<4;i++) xv[i]=Xs[kk][ty*4+i];
      #pragma unroll
      for(int j=0;j<4;j++) wv[j]=Wsh[kk][tx*4+j];
      #pragma unroll
      for(int i=0;i<4;i++)
        #pragma unroll
        for(int j=0;j<4;j++) acc[i][j]=fmaf(xv[i],wv[j],acc[i][j]);
    }
    __syncthreads();
  }
  #pragma unroll
  for(int i=0;i<4;i++){
    int r=row0+ty*4+i;
    #pragma unroll
    for(int j=0;j<4;j++){
      int c=c0+tx*4+j;
      if(c<COLS_){
        float bias=(c<512)?bs[c]:bu[c-512];
        xpart[(size_t)r*CPAD_+c]=acc[i][j]+bias;
      }
    }
  }
}

// ---------------- deferred output GEMM: out = sigmoid([x,state,read]@Wo + bo) ----------------
__global__ __launch_bounds__(256) void outgemm_kernel(const float* __restrict__ X,
    const float* __restrict__ stateSeq, const float* __restrict__ readSeq,
    const float* __restrict__ Wo, const float* __restrict__ bo, float* __restrict__ out)
{
  __shared__ float Cs[32][65];
  __shared__ float Wsh[32][65];
  const int row0=blockIdx.x*64, c0=blockIdx.y*64;
  const int tid=threadIdx.x, tx=tid&15, ty=tid>>4;
  float acc[4][4]={};
  for(int k0=0;k0<898;k0+=32){
    for(int i=tid;i<32*64;i+=256){
      int kk=i&31, tt=i>>5, k=k0+kk, row=row0+tt;
      float v=0.f;
      if(k<258) v=X[(size_t)row*IN_+k];
      else if(k<770){ int b=row>>9,t=row&511; v=stateSeq[(size_t)(b*513+t)*ST_+(k-258)]; }
      else if(k<898){ int b=row>>9,t=row&511; v=readSeq[(size_t)(b*513+t)*RD_+(k-770)]; }
      Cs[kk][tt]=v;
    }
    for(int i=tid;i<32*64;i+=256){
      int cc=i&63, kk=i>>6, k=k0+kk;
      Wsh[kk][cc]=(k<898)?Wo[(size_t)k*256+(c0+cc)]:0.f;
    }
    __syncthreads();
    #pragma unroll
    for(int kk=0;kk<32;kk++){
      float xv[4],wv[4];
      #pragma unroll
      for(int i=0;i<4;i++) xv[i]=Cs[kk][ty*4+i];
      #pragma unroll
      for(int j=0;j<4;j++) wv[j]=Wsh[kk][tx*4+j];
      #pragma unroll
      for(int i=0;i<4;i++)
        #pragma unroll
        for(int j=0;j<4;j++) acc[i][j]=fmaf(xv[i],wv[j],acc[i][j]);
    }
    __syncthreads();
  }
  #pragma unroll
  for(int i=0;i<4;i++){
    int r=row0+ty*4+i;
    #pragma unroll
    for(int j=0;j<4;j++){
      int c=c0+tx*4+j;
      out[(size_t)r*256+c]=sigm(acc[i][j]+bo[c]);
    }
  }
}

// ---------------- main persistent recurrent kernel ----------------
__global__ __launch_bounds__(512, 2) void main_kernel(
    const float* __restrict__ Ws, const float* __restrict__ Wu,
    const float* __restrict__ xpart, float* __restrict__ stateSeq,
    float* __restrict__ readSeq, float* __restrict__ updBuf,
    int* __restrict__ arriveS, int* __restrict__ arriveU, int* __restrict__ go)
{
  extern __shared__ char smem[];
  // XCD-grouped mapping: all 11 blocks of batch bb land on XCD bb%8 under
  // the i%8 round-robin dispatch heuristic (perf only; correctness placement-free).
  const int bb   = blockIdx.x & 15;
  const int role = blockIdx.x >> 4;
  const int tid  = threadIdx.x;

  if (role < G_MM) {
    // ================= matmul block =================
    SmemMM& S = *(SmemMM*)smem;
    const int c  = tid % CPB_;
    const int rc = tid / CPB_;             // 0..4 active, 5 idle
    const int cg = role*CPB_ + c;
    const bool cvalid = (cg < COLS_);
    const float* Wp; int ldw, ci;
    if (cg < 512) { Wp = Ws; ldw = 512; ci = cg; }
    else          { Wp = Wu; ldw = 404; ci = cvalid ? (cg-512) : 0; }
    float wreg[128];
    if (rc < 5) {
      #pragma unroll                       // FULL unroll: static indices -> VGPRs, not scratch
      for (int j = 0; j < 128; ++j)
        wreg[j] = Wp[(size_t)(258 + rc*128 + j)*ldw + ci];
    }
    for (int t = 0; t < S_; ++t) {
      // prefetch xpart early (read-only, cached)
      float xp = 0.f;
      if (tid < CPB_ && cvalid) xp = xpart[(size_t)(bb*512 + t)*CPAD_ + cg];
      // phase A: state(t) ready once roles 0..5 finished step t-1
      if (t > 0) {
        if (tid == 0) spinCnt(&arriveS[bb*S_ + (t-1)], 6);
        __syncthreads();
      }
      // state row t: unique address, written sc1 before flag -> cached wide load is fresh
      if (tid < 128)
        ((float4*)S.comb)[tid] = ((const float4*)&stateSeq[(size_t)(bb*513 + t)*ST_])[tid];
      __syncthreads();
      float acc = 0.f;
      if (rc < 4) {                         // state rows 0..511
        const float4* cb = (const float4*)&S.comb[rc*128];
        #pragma unroll
        for (int j4 = 0; j4 < 32; ++j4) {
          float4 cv = cb[j4];
          acc = fmaf(cv.x, wreg[4*j4+0], acc);
          acc = fmaf(cv.y, wreg[4*j4+1], acc);
          acc = fmaf(cv.z, wreg[4*j4+2], acc);
          acc = fmaf(cv.w, wreg[4*j4+3], acc);
        }
      }
      // phase B: wait for read(t)
      if (tid == 0) spinCnt(&go[bb*513 + t], 1);
      __syncthreads();
      if (tid < 32)
        ((float4*)&S.comb[512])[tid] = ((const float4*)&readSeq[(size_t)(bb*513 + t)*RD_])[tid];
      __syncthreads();
      if (rc == 4) {                        // read rows 512..639
        const float4* cb = (const float4*)&S.comb[512];
        #pragma unroll
        for (int j4 = 0; j4 < 32; ++j4) {
          float4 cv = cb[j4];
          acc = fmaf(cv.x, wreg[4*j4+0], acc);
          acc = fmaf(cv.y, wreg[4*j4+1], acc);
          acc = fmaf(cv.z, wreg[4*j4+2], acc);
          acc = fmaf(cv.w, wreg[4*j4+3], acc);
        }
      }
      if (rc < 5) S.part[rc][c] = acc;
      __syncthreads();
      if (tid < CPB_ && cvalid) {
        float pre = xp + S.part[0][c] + S.part[1][c] + S.part[2][c]
                       + S.part[3][c] + S.part[4][c];
        if (cg < 512)
          AT_ST(&stateSeq[(size_t)(bb*513 + t + 1)*ST_ + cg], sigm(pre));
        else
          AT_ST(&updBuf[(size_t)((t&1)*B_ + bb)*408 + (cg - 512)], pre);
      }
      __syncthreads();   // drains vmcnt(0) in every wave before the counter bump
      if (tid == 0) {
        if (role <= 5) AT_ADD(&arriveS[bb*S_ + t]);
        if (role >= 5) AT_ADD(&arriveU[bb*S_ + t]);
      }
    }
  } else {
    // ================= memory block =================
    SmemMB& S = *(SmemMB*)smem;
    for (int i = tid; i < 64*513; i += 512) S.mem[i] = 0.01f;
    {
      float o0 = (tid == 0) ? 1.f : 0.f;
      S.wt[0][tid]=o0; S.wt[1][tid]=o0; S.dyn[0][tid]=o0; S.dyn[1][tid]=o0;
    }
    if (tid < 128) { S.es[tid>>6][tid&63]=0.f; S.ad[tid>>6][tid&63]=0.f; }
    __syncthreads();
    // prologue: P2 with zero erase/add == pure read_0 from initial wt/mem
    p2_step(S, bb, 0, readSeq, go, tid);

    for (int t = 0; t < S_-1; ++t) {
      if (tid == 0) spinCnt(&arriveU[bb*S_ + t], 5);
      __syncthreads();
      // upd row is address-reused (double buffer) -> must stay LLC-direct; 8B packed
      {
        const unsigned long long* up8 =
            (const unsigned long long*)&updBuf[(size_t)((t&1)*B_ + bb)*408];
        if (tid < 202) {
          unsigned long long v = __hip_atomic_load(&up8[tid], __ATOMIC_RELAXED,
                                                   __HIP_MEMORY_SCOPE_AGENT);
          union { unsigned long long u; float f[2]; } cv; cv.u = v;
          S.upd[2*tid]   = cv.f[0];
          S.upd[2*tid+1] = cv.f[1];
        }
      }
      __syncthreads();
      if (tid < 128) {                      // parallel: es/ad + wave-reduced key norm
        int h=tid>>6, m=tid&63; const float* u=&S.upd[h*UPH_];
        S.es[h][m]=sigm(u[8+m]);
        S.ad[h][m]=u[72+m];
        float kv=u[136+m];
        float s2=kv*kv;
        #pragma unroll
        for(int o=32;o;o>>=1) s2+=__shfl_xor(s2,o);
        if(m==0) S.smalls[20+h]=1.f/(sqrtf(s2)+1e-12f);
      } else if (tid < 130) {               // concurrent scalar smalls (other wave)
        int h = tid-128; const float* u = &S.upd[h*UPH_];
        float sp0=splus(u[0]), sp1=splus(u[1]), sp2=splus(u[2]);
        float mx=fmaxf(sp0,fmaxf(sp1,sp2));
        float e0=__expf(sp0-mx), e1=__expf(sp1-mx), e2=__expf(sp2-mx);
        float inv=1.f/(e0+e1+e2);
        S.smalls[h*3+0]=e0*inv; S.smalls[h*3+1]=e1*inv; S.smalls[h*3+2]=e2*inv;
        float j0=u[4], j1=u[5], j2=u[6];
        float mj=fmaxf(j0,fmaxf(j1,j2));
        float f0=__expf(j0-mj), f1=__expf(j1-mj), f2=__expf(j2-mj);
        float invj=1.f/(f0+f1+f2);
        S.smalls[6+h*3+0]=f0*invj; S.smalls[6+h*3+1]=f1*invj; S.smalls[6+h*3+2]=f2*invj;
        S.smalls[12+h]=sigm(u[3]);           // jd
        S.smalls[14+h]=1.f+splus(u[7]);      // gamma
        S.smalls[16+h]=splus(u[200]);        // beta
        S.smalls[18+h]=sigm(u[201]);         // g
      }
      __syncthreads();
      if (tid < 128) {
        int h=tid>>6, m=tid&63;
        S.kn[h][m]=S.upd[h*UPH_+136+m]*S.smalls[20+h];
      }
      __syncthreads();
      // ---- P1: column norms + cosine scores, softmax, mix, shift, sharpen ----
      {
        int n = tid;
        float nrm=0.f, d0=0.f, d1=0.f;
        #pragma unroll 8
        for (int m=0;m<64;m++){
          float v=S.mem[m*513+n];
          nrm=fmaf(v,v,nrm);
          d0=fmaf(S.kn[0][m],v,d0);
          d1=fmaf(S.kn[1][m],v,d1);
        }
        float inv=1.f/(sqrtf(nrm)+1e-12f);
        float sc0=S.smalls[16]*d0*inv, sc1=S.smalls[17]*d1*inv;
        float mx0=sc0, mx1=sc1; redMax2(mx0,mx1,S.red,tid);
        float ex0=__expf(sc0-mx0), ex1=__expf(sc1-mx1);
        float sm0=ex0, sm1=ex1; redSum2(sm0,sm1,S.red,tid);
        float wtk0=ex0/sm0, wtk1=ex1/sm1;
        float jd0=S.smalls[12], jd1=S.smalls[13];
        float g0=S.smalls[18],  g1=S.smalls[19];
        float w0o=S.wt[0][n], w1o=S.wt[1][n];
        float dn0=fmaf(jd0, w0o - S.dyn[0][n], S.dyn[0][n]);
        float dn1=fmaf(jd1, w1o - S.dyn[1][n], S.dyn[1][n]);
        S.dyn[0][n]=dn0; S.dyn[1][n]=dn1;
        float fx=(n==0)?1.f:0.f;
        float wm0=S.smalls[6+0]*w0o + S.smalls[6+1]*dn0 + S.smalls[6+2]*fx;
        float wm1=S.smalls[9+0]*w1o + S.smalls[9+1]*dn1 + S.smalls[9+2]*fx;
        float wc0=fmaf(g0, wtk0-wm0, wm0);
        float wc1=fmaf(g1, wtk1-wm1, wm1);
        S.wscr[0][n]=wc0; S.wscr[1][n]=wc1;
        __syncthreads();
        int np=(n+1)&511, nm=(n-1)&511;
        float wsh0=S.smalls[0]*S.wscr[0][np]+S.smalls[1]*S.wscr[0][n]+S.smalls[2]*S.wscr[0][nm];
        float wsh1=S.smalls[3]*S.wscr[1][np]+S.smalls[4]*S.wscr[1][n]+S.smalls[5]*S.wscr[1][nm];
        float gam0=S.smalls[14], gam1=S.smalls[15];
        float wp0=(wsh0>0.f)?__expf(gam0*__logf(wsh0)):0.f;
        float wp1=(wsh1>0.f)?__expf(gam1*__logf(wsh1)):0.f;
        float ds0=wp0, ds1=wp1; redSum2(ds0,ds1,S.red,tid);
        S.wt[0][n]=wp0/(ds0+1e-12f);
        S.wt[1][n]=wp1/(ds1+1e-12f);
      }
      __syncthreads();
      // ---- P2: mem update + read(t+1) + flag ----
      p2_step(S, bb, t+1, readSeq, go, tid);
    }
  }
}

// ---------------- launch ----------------
extern "C" void kernel_launch(void* const* d_in, const int* in_sizes, int n_in,
                              void* d_out, int out_size, void* d_ws, size_t ws_size,
                              hipStream_t stream) {
  (void)in_sizes; (void)n_in; (void)out_size;
  const float* X  = (const float*)d_in[0];
  const float* Ws = (const float*)d_in[1];
  const float* bs = (const float*)d_in[2];
  const float* Wo = (const float*)d_in[3];
  const float* bo = (const float*)d_in[4];
  const float* Wu = (const float*)d_in[5];
  const float* bu = (const float*)d_in[6];
  float* out = (float*)d_out;

  const size_t needed = (size_t)(XPART_F + STATE_F + READ_F + UPDB_F)*4 + (size_t)NFLAGS_*4;
  if (ws_size < needed) return;   // fail visibly rather than corrupt memory

  float* xpart    = (float*)d_ws;
  float* stateSeq = xpart + XPART_F;
  float* readSeq  = stateSeq + STATE_F;
  float* updBuf   = readSeq + READ_F;
  int*   flags    = (int*)(updBuf + UPDB_F);
  int*   arriveS  = flags;                  // B_*S_
  int*   arriveU  = flags + B_*S_;          // B_*S_
  int*   go       = flags + 2*B_*S_;        // B_*513

  hipLaunchKernelGGL(init_kernel, dim3((NFLAGS_ + 255)/256), dim3(256), 0, stream,
                     stateSeq, flags, NFLAGS_);
  hipLaunchKernelGGL(xpart_kernel, dim3(128, 15), dim3(256), 0, stream, X, Ws, Wu, bs, bu, xpart);

  (void)hipFuncSetAttribute((const void*)main_kernel,
        hipFuncAttributeMaxDynamicSharedMemorySize, (int)sizeof(SmemMB));
  void* kargs[] = { (void*)&Ws, (void*)&Wu, (void*)&xpart, (void*)&stateSeq,
                    (void*)&readSeq, (void*)&updBuf, (void*)&arriveS, (void*)&arriveU,
                    (void*)&go };
  hipLaunchCooperativeKernel((const void*)main_kernel, dim3(B_*ROLES_), dim3(512),
                             kargs, (unsigned)sizeof(SmemMB), stream);

  hipLaunchKernelGGL(outgemm_kernel, dim3(128, 4), dim3(256), 0, stream,
                     X, stateSeq, readSeq, Wo, bo, out);
}